// Round 7
// baseline (110.305 us; speedup 1.0000x reference)
//
#include <hip/hip_runtime.h>

// LIF scan, 2001 steps over 32768 fp32 neurons. Outputs (flat fp32 in d_out):
//   s_last [N], v_last [N], v_t [T*N], s_t [T*N];  N=32768, T=2001 -> 525 MB writes.
//
// Structure = round-1 (1 neuron/thread, single pass, 512 waves on 256 CUs,
// store-backpressure-paced) + paired-lane float2 stores: even lane L stores
// {v[L],v[L+1]} into v_t, odd lane L stores {s[L-1],s[L]} into s_t — one
// 512B store instruction per wave-iter instead of two 256B ones.
// Rounds 5/6 falsified heavier 16B-store structures (replay: issue-bound;
// LDS transpose: barrier-serialized at 2 waves/CU). This is the zero-overhead
// version of the same lever (vmem-instruction count).
//
// Numerics: contract(off) + explicit __fmul_rn/__fadd_rn = bit-exact vs the
// numpy mul-then-add reference (rounds 1/5). No NT stores (round 4: ~5.4 TB/s cap).

#pragma clang fp contract(off)

typedef float f32x2 __attribute__((ext_vector_type(2)));

#define T_STEPS 2001

__global__ __launch_bounds__(128) void lif_pair_kernel(
    const float* __restrict__ x,
    float* __restrict__ s_last,
    float* __restrict__ v_last,
    float* __restrict__ v_t,
    float* __restrict__ s_t,
    int n)                                   // 32768
{
    #pragma clang fp contract(off)

    const int i    = blockIdx.x * blockDim.x + threadIdx.x;
    const int lane = threadIdx.x & 63;
    const bool even = (lane & 1) == 0;

    const float dr = __fmul_rn(0.05f, x[i]);  // bit-exact hoist
    float v = 0.f;
    float s = 0.f;

    // Per-lane stream base, chosen once:
    //  even lane -> v_t + i     (stores neurons i, i+1 of row t)
    //  odd  lane -> s_t + i - 1 (stores neurons i-1, i of row t)
    // Both 8B-aligned: i even / i-1 even, rows stride n (even).
    float* const base = even ? (v_t + i) : (s_t + (i - 1));

    size_t off = 0;
    #pragma unroll 4
    for (int t = 0; t < T_STEPS; ++t) {
        float u = __fadd_rn(__fmul_rn(0.95f, v), dr);
        const bool k = u > 0.3f;
        v = k ? 0.f : u;                      // hard reset (stored value)
        s = k ? 1.f : 0.f;

        // neighbor's finished values (xor-1 = DPP quad_perm, cheap)
        const float vo = __shfl_xor(v, 1);
        const float so = __shfl_xor(s, 1);

        f32x2 val;
        val.x = even ? v  : so;
        val.y = even ? vo : s;
        *(f32x2*)(base + off) = val;          // one dwordx2 store, 512B/wave
        off += (size_t)n;
    }

    s_last[i] = s;   // s_t[-1]
    v_last[i] = v;   // final carry
}

extern "C" void kernel_launch(void* const* d_in, const int* in_sizes, int n_in,
                              void* d_out, int out_size, void* d_ws, size_t ws_size,
                              hipStream_t stream)
{
    const float* x = (const float*)d_in[0];
    const int n = in_sizes[0];               // 32768

    float* out    = (float*)d_out;
    float* s_last = out;
    float* v_last = out + n;
    float* v_t    = out + 2 * (size_t)n;
    float* s_t    = out + 2 * (size_t)n + (size_t)T_STEPS * (size_t)n;

    const int block = 128;
    const int grid  = n / block;             // 256 blocks -> 1 per CU
    lif_pair_kernel<<<grid, block, 0, stream>>>(x, s_last, v_last, v_t, s_t, n);
}

// Round 8
// 82.113 us; speedup vs baseline: 1.3433x; 1.3433x over previous
//
#include <hip/hip_runtime.h>

// Leaky-integrate-and-fire scan, 2001 steps over 16x2048 fp32 neurons.
// Outputs (concatenated flat in d_out, all fp32):
//   s_last [N], v_last [N], v_t [T*N], s_t [T*N]   with N=32768, T=2001.
// ~525 MB of coalesced writes -> pure HBM-write-bound kernel.
//
// FINAL (reverted to round-1 structure, measured 82.0 us, absmax 0.0 =
// bit-exact vs numpy). This is ~93% of the empirically achievable write
// bandwidth (fill-kernel ceiling 6.6-7.05 TB/s on the same buffer).
// Falsified alternatives (rounds 2-7):
//  - chunk+replay float4 stores: 90 us (replay issue-serialized)
//  - LDS-transpose float4 stores: 98 us (barrier-serialized @ 2 waves/CU)
//  - paired-lane float2 stores: 110 us (shuffle lengthens serial chain)
//  - nontemporal stores: cap write BW at ~5.4 TB/s
// Numerics: contract(off) + __fmul_rn/__fadd_rn forbid FMA contraction
// (default -ffp-contract=fast flips spike decisions -> round-2 failure).

#pragma clang fp contract(off)

#define T_STEPS 2001

__global__ __launch_bounds__(128) void lif_scan_kernel(
    const float* __restrict__ x,
    float* __restrict__ s_last,
    float* __restrict__ v_last,
    float* __restrict__ v_t,
    float* __restrict__ s_t,
    int n)
{
    #pragma clang fp contract(off)

    const int i = blockIdx.x * blockDim.x + threadIdx.x;
    if (i >= n) return;

    const float LEAK   = 0.95f;
    const float DRIVE  = 0.05f;  // same bits as float(1.0 - 0.95)
    const float THRESH = 0.3f;

    const float xv    = x[i];
    // Hoisted: (1-LEAK)*x is the identical product every step (bit-exact hoist).
    const float drive = __fmul_rn(DRIVE, xv);

    float v    = 0.0f;
    float spkf = 0.0f;
    size_t off = (size_t)i;

    #pragma unroll 4
    for (int t = 0; t < T_STEPS; ++t) {
        v = __fadd_rn(__fmul_rn(LEAK, v), drive);  // leak + drive
        const bool spk = v > THRESH;               // fire
        v    = spk ? 0.0f : v;                     // hard reset (stored value)
        spkf = spk ? 1.0f : 0.0f;
        v_t[off] = v;
        s_t[off] = spkf;
        off += (size_t)n;
    }

    s_last[i] = spkf;   // s_t[-1]
    v_last[i] = v;      // carry after final step
}

extern "C" void kernel_launch(void* const* d_in, const int* in_sizes, int n_in,
                              void* d_out, int out_size, void* d_ws, size_t ws_size,
                              hipStream_t stream)
{
    const float* x = (const float*)d_in[0];
    const int n = in_sizes[0];          // 16*2048 = 32768

    float* out    = (float*)d_out;
    float* s_last = out;
    float* v_last = out + n;
    float* v_t    = out + 2 * (size_t)n;
    float* s_t    = out + 2 * (size_t)n + (size_t)T_STEPS * (size_t)n;

    const int block = 128;
    const int grid  = (n + block - 1) / block;   // 256 blocks -> 1 per CU
    lif_scan_kernel<<<grid, block, 0, stream>>>(x, s_last, v_last, v_t, s_t, n);
}